// Round 1
// baseline (63.917 us; speedup 1.0000x reference)
//
#include <hip/hip_runtime.h>
#include <hip/hip_bf16.h>
#include <math.h>

typedef __bf16 bf16x8 __attribute__((ext_vector_type(8)));
typedef float  f32x4  __attribute__((ext_vector_type(4)));

#define HW 16384   // 128*128
#define CCH 64
#define OCH 64

// Unnormalized filter taps (normalized on device in fp32, matching reference _norm)
__device__ static const float FIRTAB[62] = {
  // db4 (8)
  -0.0105974017850021f, 0.0328830116668852f, 0.0308413818355607f, -0.1870348117188811f,
  -0.0279837694169839f, 0.6308807679295904f, 0.7148465705529155f, 0.2303778133088964f,
  // db6 (12)
  0.00107730108499558f, -0.00477725751101065f, -0.0005538422009938f, 0.03158203931748603f,
  0.02752286553030533f, -0.0975016055873225f, -0.12976686756709563f, 0.22626469396544f,
  0.3152503517092432f, -0.7511339080210959f, 0.4946238903984534f, 0.1115407433501095f,
  // sym6 (12)
  -0.007800708325034148f, 0.001767711864242804f, 0.04472490177066578f, -0.02106029251230056f,
  -0.0726375227866f, 0.3379294217282401f, 0.787641141030194f, 0.4910559419267466f,
  -0.048311742585632f, -0.1179901111484105f, 0.00349071208421747f, 0.01540410932702737f,
  // coif5 (30)
  -3.459977283621256e-05f, -7.098330313814114e-05f, 0.0004662169601128863f, 0.001117518770890601f,
  -0.002574517688750223f, -0.00900797613666158f, 0.015880544863615904f, 0.03455502757306163f,
  -0.08230192710688598f, -0.07179982161931202f, 0.42848347637761874f, 0.7937772226256206f,
  0.4051769024096169f, -0.06112339000267287f, -0.06577191128185562f, 0.023452696141836267f,
  0.007782596427325418f, -0.003793512864491014f, -0.0002606761356811993f, 0.000107502882505652f,
  1.10319778524429e-05f, -5.520763127949e-06f, -1.0682196848076e-06f, 5.236425333584e-07f,
  1.125098976034e-07f, -5.417490769329e-08f, -8.8631e-09f, 4.2921e-09f, 6.7e-10f, -3.2e-10f
};
__device__ static const int FIR_OFF[4] = {0, 8, 20, 32};
__device__ static const int FIR_LEN[4] = {8, 12, 12, 30};

// ---------------------------------------------------------------------------
// Kernel 1: build P_k (64x64) = pwA @ M_k + pwD @ N_k for k=0..5, write bf16
// in MFMA fragment-linear layout:
//   entry (k, o, c) -> slot[((s*4+mf)*64 + lane)*8 + e]
//   s = 2k + (c>>5), mf = o>>4, lane = (o&15) | (((c&31)>>3)<<4), e = c&7
// One block per k. Threads 0..63: basis column c. All 256: projection stage.
// ---------------------------------------------------------------------------
__global__ __launch_bounds__(256) void setup_P(
    const float* __restrict__ pw,      // proj_w [64][128]
    const float* __restrict__ s53A, const float* __restrict__ s53D,
    const float* __restrict__ s97A, const float* __restrict__ s97D,
    __bf16* __restrict__ Pout)
{
  __shared__ float matA[64][64];
  __shared__ float matD[64][64];
  __shared__ float tmpA[62][64];
  __shared__ float tmpD[62][64];

  const int k = blockIdx.x;
  const int t = threadIdx.x;

  if (t < 64) {
    const int c = t;
    int Lin;
    if (k < 4) {
      // FIR: cross-correlation (lax.conv does not flip), reflect pad (pl, pr)
      const int L  = FIR_LEN[k];
      const int off = FIR_OFF[k];
      const int pad = (L - 1) / 2;      // even L -> pl = pad-1
      const int pl  = pad - 1;
      float ss = 0.f;
      for (int l = 0; l < L; ++l) { float v = FIRTAB[off + l]; ss += v * v; }
      const float inv = 1.f / (sqrtf(ss) + 1e-12f);

      for (int i = 0; i < 62; ++i) { tmpA[i][c] = 0.f; tmpD[i][c] = 0.f; }
      // A62[i] = sum_l lo[l] * [refl(i + l - pl) == c]
      // refl(u)==c  <=>  u==c  |  u==-c (c>0)  |  u==126-c (c<63)
      for (int l = 0; l < L; ++l) {
        const float lov = FIRTAB[off + l] * inv;
        const float hiv = ((l & 1) ? -1.f : 1.f) * FIRTAB[off + L - 1 - l] * inv;
        const int base = pl - l;
        int i0 = c + base;
        if (i0 >= 0 && i0 < 62) { tmpA[i0][c] += lov; tmpD[i0][c] += hiv; }
        if (c > 0) {
          int i1 = -c + base;
          if (i1 >= 0 && i1 < 62) { tmpA[i1][c] += lov; tmpD[i1][c] += hiv; }
        }
        if (c < 63) {
          int i2 = 126 - c + base;
          if (i2 >= 0 && i2 < 62) { tmpA[i2][c] += lov; tmpD[i2][c] += hiv; }
        }
      }
      Lin = 62;
    } else {
      // Lifting on basis vector: even in tmpA rows 0..31, odd in tmpD rows 0..31
      for (int i = 0; i < 32; ++i) {
        tmpA[i][c] = (c == 2 * i)     ? 1.f : 0.f;
        tmpD[i][c] = (c == 2 * i + 1) ? 1.f : 0.f;
      }
      float cf[4]; int nst;
      if (k == 4) { cf[0] = -0.5f; cf[1] = 0.25f; cf[2] = 0.f; cf[3] = 0.f; nst = 2; }
      else { cf[0] = -1.586134342f; cf[1] = -0.05298011854f;
             cf[2] = 0.8829110762f; cf[3] = 0.4435068522f; nst = 4; }
      for (int s = 0; s < nst; ++s) {
        if ((s & 1) == 0) { // predict: odd += cf * ns(even)
          for (int i = 0; i < 32; ++i) {
            float a = tmpA[(i == 0) ? 1 : i - 1][c];
            float b2 = tmpA[(i == 31) ? 30 : i + 1][c];
            tmpD[i][c] += cf[s] * 0.5f * (a + b2);
          }
        } else {            // update: even += cf * ns(odd)
          for (int i = 0; i < 32; ++i) {
            float a = tmpD[(i == 0) ? 1 : i - 1][c];
            float b2 = tmpD[(i == 31) ? 30 : i + 1][c];
            tmpA[i][c] += cf[s] * 0.5f * (a + b2);
          }
        }
      }
      Lin = 32;
    }
    // scales
    float sA = 1.f, sD = 1.f;
    if (k == 4) { sA = s53A[0]; sD = s53D[0]; }
    if (k == 5) { sA = s97A[0]; sD = s97D[0]; }
    // resize Lin -> 64 (matches _resize_linear)
    const float step = (float)Lin / 64.0f;
    for (int o = 0; o < 64; ++o) {
      float src = (o + 0.5f) * step - 0.5f;
      src = fmaxf(src, 0.f);
      int i0 = (int)floorf(src); if (i0 > Lin - 1) i0 = Lin - 1;
      int i1 = i0 + 1;           if (i1 > Lin - 1) i1 = Lin - 1;
      float w = src - (float)i0;
      matA[o][c] = sA * ((1.f - w) * tmpA[i0][c] + w * tmpA[i1][c]);
      matD[o][c] = sD * ((1.f - w) * tmpD[i0][c] + w * tmpD[i1][c]);
    }
  }
  __syncthreads();

  // Projection fold: P_k[o][c] = sum_j pw[o][j]*matA[j][c] + pw[o][64+j]*matD[j][c]
  const int o  = t & 63;
  const int cb = (t >> 6) * 16;
  float acc[16];
  #pragma unroll
  for (int cc = 0; cc < 16; ++cc) acc[cc] = 0.f;
  for (int j = 0; j < 64; ++j) {
    const float wa = pw[o * 128 + j];
    const float wd = pw[o * 128 + 64 + j];
    #pragma unroll
    for (int cc = 0; cc < 16; ++cc)
      acc[cc] += wa * matA[j][cb + cc] + wd * matD[j][cb + cc];
  }
  const int mf = o >> 4;
  #pragma unroll
  for (int cc = 0; cc < 16; ++cc) {
    const int c = cb + cc;
    const int s = k * 2 + (c >> 5);
    const int lane = (o & 15) | (((c & 31) >> 3) << 4);
    const int e = c & 7;
    Pout[(((s * 4 + mf) * 64 + lane) << 3) + e] = (__bf16)acc[cc];
  }
}

// ---------------------------------------------------------------------------
// Kernel 2: per block = 128 pixels of one batch image.
//  - stage P (48KB) into LDS
//  - threads 0..127: load channel column (coalesced), gate MLP+softmax,
//    write bf16 x-row to LDS (stride 88 bf16, 16B-aligned, ~2-way conflicts)
//  - 4 waves x 32 pixels: per k, Y_k = P_k @ X (2 MFMAs per 16x16 tile),
//    out += wm[k,p] * Y_k; epilogue adds proj_b, coalesced fp32 stores
// ---------------------------------------------------------------------------
#define XSTR 88  // bf16 elements per xtr row

__global__ __launch_bounds__(256) void wavelet_main(
    const float* __restrict__ xg,
    const float* __restrict__ gw1, const float* __restrict__ gb1,
    const float* __restrict__ gw2, const float* __restrict__ gb2,
    const float* __restrict__ pbias,
    const __bf16* __restrict__ Pws,
    float* __restrict__ outg)
{
  __shared__ __align__(16) __bf16 Plds[12 * 4 * 64 * 8];   // 49152 B
  __shared__ __align__(16) __bf16 xtr[128 * XSTR];         // 22528 B
  __shared__ float wmlds[128 * 8];                         //  4096 B

  const int t = threadIdx.x;
  const int blk = blockIdx.x;
  const int b = blk >> 7;                 // 128 tiles per batch image
  const int pbase = (blk & 127) << 7;     // 128 pixels per tile

  // stage P: 3072 float4 / 256 threads = 12 each
  {
    const float4* src = (const float4*)Pws;
    float4* dst = (float4*)Plds;
    #pragma unroll
    for (int i = 0; i < 12; ++i) dst[t + i * 256] = src[t + i * 256];
  }

  if (t < 128) {
    const int p = pbase + t;
    const float* xp = xg + (size_t)b * CCH * HW + p;
    float xr[64];
    #pragma unroll
    for (int c = 0; c < 64; ++c) xr[c] = xp[(size_t)c * HW];

    // transposed bf16 tile row
    #pragma unroll
    for (int i = 0; i < 8; ++i) {
      bf16x8 v;
      #pragma unroll
      for (int e = 0; e < 8; ++e) v[e] = (__bf16)xr[i * 8 + e];
      *(bf16x8*)&xtr[t * XSTR + i * 8] = v;
    }

    // gate MLP (weights wave-uniform -> scalar loads)
    float h[16];
    #pragma unroll
    for (int g = 0; g < 16; ++g) {
      float a = gb1[g];
      #pragma unroll
      for (int c = 0; c < 64; ++c) a += xr[c] * gw1[g * 64 + c];
      h[g] = fmaxf(a, 0.f);
    }
    float lg[6];
    #pragma unroll
    for (int kk = 0; kk < 6; ++kk) {
      float a = gb2[kk];
      #pragma unroll
      for (int g = 0; g < 16; ++g) a += h[g] * gw2[kk * 16 + g];
      lg[kk] = a;
    }
    float mx = lg[0];
    #pragma unroll
    for (int kk = 1; kk < 6; ++kk) mx = fmaxf(mx, lg[kk]);
    float ex[6], ssum = 0.f;
    #pragma unroll
    for (int kk = 0; kk < 6; ++kk) { ex[kk] = expf(lg[kk] - mx); ssum += ex[kk]; }
    float g6[6], wsum = 0.f;
    #pragma unroll
    for (int kk = 0; kk < 6; ++kk) { g6[kk] = ex[kk] / ssum; wsum += g6[kk]; }
    const float winv = 1.f / (wsum + 1e-12f);
    #pragma unroll
    for (int kk = 0; kk < 6; ++kk) wmlds[t * 8 + kk] = g6[kk] * winv;
  }
  __syncthreads();

  const int w    = t >> 6;
  const int lane = t & 63;
  const int lr   = lane & 15;
  const int kq   = lane >> 4;

  // bias values for this lane's 16 output rows
  float bvv[16];
  #pragma unroll
  for (int mf = 0; mf < 4; ++mf)
    #pragma unroll
    for (int j = 0; j < 4; ++j)
      bvv[mf * 4 + j] = pbias[mf * 16 + kq * 4 + j];

  #pragma unroll
  for (int n = 0; n < 2; ++n) {
    const int pbl = w * 32 + n * 16;
    const int col = pbl + lr;

    const bf16x8 B0 = *(const bf16x8*)&xtr[col * XSTR + kq * 8];
    const bf16x8 B1 = *(const bf16x8*)&xtr[col * XSTR + 32 + kq * 8];

    float wmv[6];
    #pragma unroll
    for (int kk = 0; kk < 6; ++kk) wmv[kk] = wmlds[col * 8 + kk];

    f32x4 facc[4];
    #pragma unroll
    for (int mf = 0; mf < 4; ++mf) { f32x4 z = {0.f, 0.f, 0.f, 0.f}; facc[mf] = z; }

    #pragma unroll
    for (int kk = 0; kk < 6; ++kk) {
      #pragma unroll
      for (int mf = 0; mf < 4; ++mf) {
        const bf16x8 A0 = *(const bf16x8*)&Plds[(((2 * kk) * 4 + mf) * 64 + lane) * 8];
        const bf16x8 A1 = *(const bf16x8*)&Plds[(((2 * kk + 1) * 4 + mf) * 64 + lane) * 8];
        f32x4 y = {0.f, 0.f, 0.f, 0.f};
        y = __builtin_amdgcn_mfma_f32_16x16x32_bf16(A0, B0, y, 0, 0, 0);
        y = __builtin_amdgcn_mfma_f32_16x16x32_bf16(A1, B1, y, 0, 0, 0);
        #pragma unroll
        for (int j = 0; j < 4; ++j) facc[mf][j] += wmv[kk] * y[j];
      }
    }

    float* outp = outg + (size_t)b * OCH * HW + (size_t)(pbase + pbl + lr);
    #pragma unroll
    for (int mf = 0; mf < 4; ++mf) {
      #pragma unroll
      for (int j = 0; j < 4; ++j) {
        const int o = mf * 16 + kq * 4 + j;
        outp[(size_t)o * HW] = facc[mf][j] + bvv[mf * 4 + j];
      }
    }
  }
}

extern "C" void kernel_launch(void* const* d_in, const int* in_sizes, int n_in,
                              void* d_out, int out_size, void* d_ws, size_t ws_size,
                              hipStream_t stream) {
  const float* x    = (const float*)d_in[0];
  const float* gw1  = (const float*)d_in[1];
  const float* gb1  = (const float*)d_in[2];
  const float* gw2  = (const float*)d_in[3];
  const float* gb2  = (const float*)d_in[4];
  const float* pw   = (const float*)d_in[5];
  const float* pb   = (const float*)d_in[6];
  const float* s53A = (const float*)d_in[7];
  const float* s53D = (const float*)d_in[8];
  const float* s97A = (const float*)d_in[9];
  const float* s97D = (const float*)d_in[10];
  __bf16* Pws = (__bf16*)d_ws;
  float* out = (float*)d_out;

  setup_P<<<6, 256, 0, stream>>>(pw, s53A, s53D, s97A, s97D, Pws);
  wavelet_main<<<1024, 256, 0, stream>>>(x, gw1, gb1, gw2, gb2, pb, Pws, out);
}